// Round 2
// baseline (88.196 us; speedup 1.0000x reference)
//
#include <hip/hip_runtime.h>
#include <hip/hip_bf16.h>
#include <math.h>

// Problem constants (reference: N_NODES=2048, N_ATTRS=64, TOP_K=8)
#define NN 2048
#define NF 64
#define KK 8
#define C  16    // scan chunk size (elements per bound-check)

// Device-global scratch (static .so allocation — avoids d_ws sizing risk).
// Fully rewritten by order_kernel on every call: no cross-call state.
__device__ float    g_xs[NF * NN];   // x values, per-f bucket-descending order
__device__ unsigned g_xi[NF * NN];   // source node index per position
__device__ float    g_sm[NF * NN];   // EXACT suffix max of g_xs (exit bound)

// ---------------- Kernel 1: per-feature approximate-descending order ------
// One block per feature f. 256-bucket counting sort by value (monotone
// mapping), then exact suffix-max scan. Correctness of the whole algorithm
// only needs (a) a complete permutation and (b) the exact suffix max —
// bucket quality affects speed only.
__global__ __launch_bounds__(1024)
void order_kernel(const float* __restrict__ x) {
  __shared__ int   hist[256];
  __shared__ int   scan[256];
  __shared__ int   offs[256];
  __shared__ float svals[NN];
  const int f = blockIdx.x;
  const int tid = threadIdx.x;

  if (tid < 256) hist[tid] = 0;
  __syncthreads();

  // Each thread owns elements tid and tid+1024.
  float v0 = x[(size_t)tid * NF + f];
  float v1 = x[(size_t)(tid + 1024) * NF + f];
  int b0 = (int)((3.6f - v0) * 35.4f); b0 = b0 < 0 ? 0 : (b0 > 255 ? 255 : b0);
  int b1 = (int)((3.6f - v1) * 35.4f); b1 = b1 < 0 ? 0 : (b1 > 255 ? 255 : b1);
  atomicAdd(&hist[b0], 1);
  atomicAdd(&hist[b1], 1);
  __syncthreads();

  // Exclusive prefix sum over 256 buckets (Hillis-Steele; barriers are
  // block-uniform — work is guarded, barriers are not).
  if (tid < 256) scan[tid] = hist[tid];
  __syncthreads();
  for (int d = 1; d < 256; d <<= 1) {
    int o = 0;
    if (tid < 256 && tid >= d) o = scan[tid - d];
    __syncthreads();
    if (tid < 256) scan[tid] += o;
    __syncthreads();
  }
  if (tid < 256) offs[tid] = scan[tid] - hist[tid];
  __syncthreads();

  // Scatter into bucket-ordered positions (within-bucket order arbitrary).
  int p0 = atomicAdd(&offs[b0], 1);
  int p1 = atomicAdd(&offs[b1], 1);
  svals[p0] = v0;
  svals[p1] = v1;
  g_xs[f * NN + p0] = v0;  g_xi[f * NN + p0] = (unsigned)tid;
  g_xs[f * NN + p1] = v1;  g_xi[f * NN + p1] = (unsigned)(tid + 1024);
  __syncthreads();

  // Exact suffix max (in place, read-before-sync / write-after-sync).
  for (int d = 1; d < NN; d <<= 1) {
    float o0 = (tid + d < NN) ? svals[tid + d] : -INFINITY;
    float o1 = (tid + 1024 + d < NN) ? svals[tid + 1024 + d] : -INFINITY;
    __syncthreads();
    svals[tid]        = fmaxf(svals[tid], o0);
    svals[tid + 1024] = fmaxf(svals[tid + 1024], o1);
    __syncthreads();
  }
  g_sm[f * NN + tid]        = svals[tid];
  g_sm[f * NN + tid + 1024] = svals[tid + 1024];
}

// ---------------- Kernel 2: pruned top-8 scan -----------------------------
// Branchless sorted insert: only t[7] may be new, one bubble pass restores
// descending order. 15 VALU ops, no divergence.
__device__ __forceinline__ void ins8(float (&t)[KK], float p) {
  t[7] = fmaxf(t[7], p);
#pragma unroll
  for (int s = KK - 1; s >= 1; --s) {
    float hi = fmaxf(t[s - 1], t[s]);
    float lo = fminf(t[s - 1], t[s]);
    t[s - 1] = hi;
    t[s] = lo;
  }
}

// Block = 64 j (lanes) x 8 f (waves). adj loads coalesced across lanes;
// x/idx/bound loads are wave-uniform (L1 broadcast). Early exit is exact:
// stop when every lane's 8th-best >= max(suffix_max, 0) — no remaining
// product adj*xv can exceed max(xv,0) since adj in [0,1) (ties cannot
// change the top-8 VALUES, and rounding cannot push adj*xv above xv).
__global__ __launch_bounds__(512)
void topk_kernel(const float* __restrict__ x, const float* __restrict__ adj,
                 float* __restrict__ out) {
  const int tid  = threadIdx.x;
  const int lane = tid & 63;
  const int w    = tid >> 6;           // wave id = feature within group
  const int jt   = blockIdx.x & 31;    // 32 j tiles
  const int fg   = blockIdx.x >> 5;    // 8 f groups
  const int f    = (fg << 3) + w;
  const int j    = (jt << 6) + lane;

  const float*    vp = g_xs + f * NN;
  const unsigned* ip = g_xi + f * NN;
  const float*    sp = g_sm + f * NN;

  float t8[KK];
#pragma unroll
  for (int s = 0; s < KK; ++s) t8[s] = -INFINITY;

  int t = 0;
  for (;;) {
    // Uniform chunk loads as vectors (broadcast, L1-resident).
    const float4* vp4 = (const float4*)(vp + t);
    const uint4*  ip4 = (const uint4*)(ip + t);
    float4 xv4[4];
    uint4  xi4[4];
#pragma unroll
    for (int q = 0; q < 4; ++q) { xv4[q] = vp4[q]; xi4[q] = ip4[q]; }

    // 16 independent coalesced adj loads (ILP hides L2/L3 latency).
    float a[C];
#pragma unroll
    for (int q = 0; q < 4; ++q) {
      a[q * 4 + 0] = adj[((size_t)xi4[q].x << 11) + j];
      a[q * 4 + 1] = adj[((size_t)xi4[q].y << 11) + j];
      a[q * 4 + 2] = adj[((size_t)xi4[q].z << 11) + j];
      a[q * 4 + 3] = adj[((size_t)xi4[q].w << 11) + j];
    }
#pragma unroll
    for (int q = 0; q < 4; ++q) {
      ins8(t8, a[q * 4 + 0] * xv4[q].x);
      ins8(t8, a[q * 4 + 1] * xv4[q].y);
      ins8(t8, a[q * 4 + 2] * xv4[q].z);
      ins8(t8, a[q * 4 + 3] * xv4[q].w);
    }

    t += C;
    if (t >= NN) break;
    float bound = fmaxf(sp[t], 0.0f);   // exact max of all remaining xv
    if (__all(t8[KK - 1] >= bound)) break;
  }

  // Stage results; write out[j, s, f] as float4 runs (32B-sector aligned
  // per 8-f group -> no HBM read-modify-write).
  __shared__ float obuf[KK + 1][64][8];   // [s][j][f] , 18 KiB
  obuf[0][lane][w] = x[(size_t)j * NF + f];
#pragma unroll
  for (int s = 0; s < KK; ++s) obuf[s + 1][lane][w] = t8[s];
  __syncthreads();

  const int f0 = fg << 3;
  for (int r = tid; r < (KK + 1) * 64 * 2; r += 512) {
    int rs  = r >> 7;          // 0..8
    int rem = r & 127;
    int rj  = rem >> 1;        // 0..63
    int h   = rem & 1;         // which float4 of the 8-f group
    float4 v = make_float4(obuf[rs][rj][h * 4 + 0], obuf[rs][rj][h * 4 + 1],
                           obuf[rs][rj][h * 4 + 2], obuf[rs][rj][h * 4 + 3]);
    *(float4*)(out + (size_t)((jt << 6) + rj) * ((KK + 1) * NF) +
               rs * NF + f0 + (h << 2)) = v;
  }
}

extern "C" void kernel_launch(void* const* d_in, const int* in_sizes, int n_in,
                              void* d_out, int out_size, void* d_ws, size_t ws_size,
                              hipStream_t stream) {
  const float* x   = (const float*)d_in[0];   // (2048, 64) f32
  const float* adj = (const float*)d_in[1];   // (2048, 2048) f32
  float* out = (float*)d_out;                 // (2048, 9, 64) f32
  hipLaunchKernelGGL(order_kernel, dim3(NF), dim3(1024), 0, stream, x);
  hipLaunchKernelGGL(topk_kernel, dim3(256), dim3(512), 0, stream, x, adj, out);
}